// Round 12
// baseline (159.445 us; speedup 1.0000x reference)
//
#include <hip/hip_runtime.h>
#include <hip/hip_bf16.h>

// DynamicFilter fused, R26 = R25 (spill-free) with xs0f folded into hs spare
// slots to restore 4 blocks/CU.
//
// R25 post-mortem: spills gone (WRITE exactly 8192KB, VGPR 116) but
// 93.2 -> 100.4us: LDS 36.9 -> 41.5KB crossed 40KB -> 3 blocks/CU; grid is
// exactly 4/CU so 256-block tail ran at 1/3 occupancy (+7us drain).
// R26: hs px slots are 40 shorts, only 32 used. Stash fp32 image in the
// spare dword (short +32): epilogue's image reads live exactly on h-grid
// px 1..18. Delete xs0f (-2304B) -> LDS 38912 -> 4 blocks/CU, no tail,
// fp32 image numerics EXACT. Stage writes img via precomputed hpos[k];
// epilogue reads float at py*800 + n*40 + o2(f), o2 = 800fy+40fx+872,
// clamped to 872 for f>=9 (term is exact-zero via acc=0; clamp avoids
// NaN-pattern garbage from w1l region at rows>19).
// Predict: LDS ~38.9KB, main 100.4 -> 84-90us, WRITE exactly 8192KB,
// VGPR ~118-124, conflicts ~9.5e6. If flat vs R24's 93: spill residue was
// free -> LDS-pipe stream is the wall -> cut hs traffic structurally next.
//
// LDS: pxc 2.3K + hs 32K (ch-data + fp32 img stash) + w1l 4.6K = 38.9KB.
// d_ws: w1c bf16 [32ch][64k] @0 (k-perm layout), w2t bf16 [25tap][16f]
// [32chpos] @4096 (f>=9 zero; chpos 2i->ch i, 2i+1->ch 16+i).
// k-perm: k = s*32+kg*8+2*j+ci ; s0: tap=(kg,j); s1,kg0: tap=(4,j);
// s1,kg1: tap=(j,4); s1,kg2,j0: tap=(4,4); else invalid (w1c=0).

typedef __attribute__((ext_vector_type(8))) short bf16x8;
typedef __attribute__((ext_vector_type(4))) float f32x4;

#define HH 512
#define WW 512
#define TILE 16
#define XS_H 24
#define XS_W 24
#define XS_N (XS_H * XS_W)     // 576
#define HS_R 20
#define HS_C 20
#define PXS 40                 // shorts per px in hs (80B stride; 32 ch + 4 spare dwords)
#define W1S 72                 // w1l row stride in shorts (144B: aligned+spread)

__device__ __forceinline__ unsigned short f2bf(float x) {
    union { float f; unsigned int u; } v; v.f = x;
    unsigned int u = v.u;
    u += 0x7FFFu + ((u >> 16) & 1u);   // round-to-nearest-even
    return (unsigned short)(u >> 16);
}

__device__ __forceinline__ unsigned int pack_bf2(float a, float b) {
    __hip_bfloat162 h2 = __float22bfloat162_rn(make_float2(a, b));
    union { __hip_bfloat162 h; unsigned int u; } cv; cv.h = h2;
    return cv.u;
}

__device__ __forceinline__ bf16x8 dw4_to_frag(unsigned int d0, unsigned int d1,
                                              unsigned int d2, unsigned int d3) {
    union { unsigned int u[4]; bf16x8 f; } cv;
    cv.u[0] = d0; cv.u[1] = d1; cv.u[2] = d2; cv.u[3] = d3;
    return cv.f;
}

__global__ void dynfilt_prep(const float* __restrict__ w1,
                             const float* __restrict__ w2,
                             unsigned short* __restrict__ w1c,
                             unsigned short* __restrict__ w2t)
{
    int gid = blockIdx.x * 256 + threadIdx.x;   // 8192 threads
    // w1c[ch32][k64] with k-perm (see header); invalid slots -> 0
    for (int i = gid; i < 32 * 64; i += 8192) {
        int ch = i >> 6, k = i & 63;
        int s = (k >> 5) & 1, kg = (k >> 3) & 3, j = (k >> 1) & 3, ci = k & 1;
        int tap = 0; bool val = true;
        if (!s)            tap = kg * 5 + j;        // rows 0-3, cols 0-3
        else if (kg == 0)  tap = 20 + j;            // row 4, cols 0-3
        else if (kg == 1)  tap = j * 5 + 4;         // col 4, rows 0-3
        else if (kg == 2) { tap = 24; val = (j == 0); }   // corner (4,4)
        else               val = false;
        w1c[i] = val ? f2bf(w1[(ch * 2 + ci) * 25 + tap]) : (unsigned short)0;
    }
    // w2t[tap25][f16][chpos32]: chpos 2i -> ch i, 2i+1 -> ch 16+i; f>=9 zero
    for (int i = gid; i < 25 * 16 * 32; i += 8192) {
        int p = i & 31;
        int f = (i >> 5) & 15;
        int tap = i >> 9;   // 0..24
        int ch = (p & 1) * 16 + (p >> 1);
        w2t[i] = (f < 9) ? f2bf(w2[(f * 32 + ch) * 25 + tap]) : (unsigned short)0;
    }
}

// conv2 pass over single tap-col TC0: rolling 4-row B-frag buffer.
// B-frag(row = wv*4 + i + tr, col = n + TC0) shared across (i,tr) with equal
// i+tr; rows rotate through R[.&3]. All indices compile-time after unroll.
template<int TC0>
__device__ __forceinline__ void conv2_pass(const unsigned short* hsp,
                                           const unsigned short* __restrict__ w2t,
                                           int wv, int n, int kg, f32x4* acc) {
    bf16x8 R[4];
    #pragma unroll
    for (int q = 0; q < 4; ++q)
        R[q] = *(const bf16x8*)(hsp + ((wv * 4 + q) * HS_C + n + TC0) * PXS + kg * 8);
    #pragma unroll
    for (int tr = 0; tr < 5; ++tr) {
        bf16x8 afr = *(const bf16x8*)(w2t + ((tr * 5 + TC0) * 16 + n) * 32 + kg * 8);
        #pragma unroll
        for (int i = 0; i < 4; ++i)
            acc[i] = __builtin_amdgcn_mfma_f32_16x16x32_bf16(afr, R[(tr + i) & 3], acc[i], 0, 0, 0);
        if (tr < 4)
            R[tr & 3] = *(const bf16x8*)(hsp + ((wv * 4 + tr + 4) * HS_C + n + TC0) * PXS + kg * 8);
    }
}

__global__
__attribute__((amdgpu_flat_work_group_size(256, 256), amdgpu_waves_per_eu(2)))
void dynfilt_main(const float* __restrict__ image,
                  const float* __restrict__ refer,
                  const float* __restrict__ b1,
                  const float* __restrict__ b2,
                  const unsigned short* __restrict__ w1c,
                  const unsigned short* __restrict__ w2t,
                  float* __restrict__ out)
{
    __shared__ unsigned int pxc[XS_N];          // packed (bf16 img | bf16 ref)
    __shared__ __align__(16) unsigned short hs[HS_R * HS_C * PXS];
    __shared__ __align__(16) unsigned short w1l[32 * W1S];   // w1c LDS stash

    const int t   = threadIdx.x;
    const int gx0 = blockIdx.x * TILE;
    const int gy0 = blockIdx.y * TILE;

    // whole halo (rows gy0-4..+19, cols gx0-4..+19) in-bounds?
    const bool interior = (gy0 >= 4) && (gy0 + XS_H - 4 <= HH) &&
                          (gx0 >= 4) && (gx0 + XS_W - 4 <= WW);

    // ---- stage w1c -> w1l (once per block; 1024 dwords, 4/thread) ----
    {
        const unsigned int* src = (const unsigned int*)w1c;
        #pragma unroll
        for (int k = 0; k < 4; ++k) {
            int i = t + k * 256;                 // 0..1023
            int ch = i >> 5, kd = i & 31;        // 32 dwords per ch row
            *(unsigned int*)(w1l + ch * W1S + kd * 2) = src[i];
        }
    }

    // ---- batch-invariant staging offsets (sentinel -1 = skip) ----
    int soff[3];
    int hpos[3];                                 // hs img-stash short offset
    #pragma unroll
    for (int k = 0; k < 3; ++k) {
        int idx = t + k * 256;
        int r = idx / XS_W, c = idx - (idx / XS_W) * XS_W;
        int gy = gy0 - 4 + r, gx = gx0 - 4 + c;
        bool inb = (idx < XS_N) & ((unsigned)gy < HH) & ((unsigned)gx < WW);
        soff[k] = inb ? (gy * WW + gx) : -1;
        bool hv = (idx < XS_N) & (r >= 2) & (r < 22) & (c >= 2) & (c < 22);
        hpos[k] = hv ? (((r - 2) * HS_C + (c - 2)) * PXS + 32) : -1;
    }

    const int lane = t & 63;
    const int wv   = t >> 6;
    const int n    = lane & 15;
    const int kg   = lane >> 4;

    // ---- a1 gather offsets (k-perm layout), packed 4x8bit; invalid -> 0
    //      (broadcast read, zero weight in w1c makes the product exact-0) ----
    unsigned int a1opk = 0;
    #pragma unroll
    for (int j = 0; j < 4; ++j) {
        int o = (kg == 0) ? (4 * XS_W + j)                  // row 4, col j
              : (kg == 1) ? (j * XS_W + 4)                  // row j, col 4
              : (kg == 2 && j == 0) ? (4 * XS_W + 4) : 0;   // corner / dummy
        a1opk |= (unsigned)o << (8 * j);
    }

    // px = mt*16 + n raster start (pr0,pc0) over 20-wide h grid
    int px0 = wv * 16 + n;
    const int pr0 = px0 / 20, pc0 = px0 - (px0 / 20) * 20;

    const float bb0 = b1[n], bb1 = b1[16 + n];

    // ---- conv2 / epilogue constants (once); img offsets packed 2x16bit ----
    float b2r[4];
    unsigned int eop2[2] = {0u, 0u};
    #pragma unroll
    for (int r2 = 0; r2 < 4; ++r2) {
        int f = kg * 4 + r2;
        b2r[r2] = (f < 9) ? b2[f] : 0.f;
        int fy = f / 3, fx = f - fy * 3;
        // hs img stash: shorts = 800*(py+fy+1) + 40*(n+fx+1) + 32
        //             = py*800 + n*40 + (800*fy + 40*fx + 872)
        unsigned int o = (f < 9) ? (unsigned)(800 * fy + 40 * fx + 872) : 872u;
        eop2[r2 >> 1] |= o << ((r2 & 1) * 16);
    }

    // ---- prefetch batch 0 halo into regs ----
    float pvI[3], pvR[3];
    #pragma unroll
    for (int k = 0; k < 3; ++k) {
        pvI[k] = 0.f; pvR[k] = 0.f;
        if (soff[k] >= 0) {
            pvI[k] = image[soff[k]];
            pvR[k] = refer[soff[k]];
        }
    }

    #pragma unroll 1
    for (int bb = 0; bb < 8; ++bb) {
        // ---- stage write from prefetch regs: pxc + hs img stash ----
        #pragma unroll
        for (int k = 0; k < 3; ++k) {
            int idx = t + k * 256;
            if (idx < XS_N)
                pxc[idx] = pack_bf2(pvI[k], pvR[k]);
            if (hpos[k] >= 0)
                *(float*)(hs + hpos[k]) = pvI[k];
        }
        __syncthreads();   // A: pxc + hs img ready (and w1l on iter 0)

        // ---- issue next batch's prefetch (hides under conv1+conv2) ----
        if (bb < 7) {
            const float* ibn = image + (size_t)(bb + 1) * (HH * WW);
            const float* rbn = refer + (size_t)(bb + 1) * (HH * WW);
            #pragma unroll
            for (int k = 0; k < 3; ++k) {
                pvI[k] = 0.f; pvR[k] = 0.f;
                if (soff[k] >= 0) {
                    pvI[k] = ibn[soff[k]];
                    pvR[k] = rbn[soff[k]];
                }
            }
        }

        // ---- conv1 B-frags: reloaded per iter from LDS stash (laundered
        //      ptr blocks LICM -> 16 regs dead during conv2; ~120cy, hidden) ----
        int lz = 0;
        asm volatile("" : "+v"(lz));
        const unsigned short* w1p = w1l + lz;
        bf16x8 bfr[2][2];
        #pragma unroll
        for (int nt = 0; nt < 2; ++nt)
            #pragma unroll
            for (int s = 0; s < 2; ++s)
                bfr[nt][s] = *(const bf16x8*)(w1p + (nt * 16 + n) * W1S + s * 32 + kg * 8);

        // ---- unpack a1 offsets (conv1-local regs) ----
        int a1o[4];
        #pragma unroll
        for (int j = 0; j < 4; ++j)
            a1o[j] = (int)((a1opk >> (8 * j)) & 0xFFu);

        // ---- conv1 GEMM + fused leaky+pack write to hs ----
        int pr = pr0, pc = pc0;
        if (interior) {
            unsigned short* hp0 = hs + (wv * 16 + kg * 4) * PXS + 2 * n;
            #pragma unroll
            for (int m = 0; m < 7; ++m) {
                int mt = m * 4 + wv;
                if (mt < 25) {   // wave-uniform guard
                    const unsigned int* base = pxc + (pr * XS_W + pc);
                    const unsigned int* a0p  = base + kg * XS_W;   // row kg
                    unsigned int a0d[4], a1d[4];
                    #pragma unroll
                    for (int j = 0; j < 4; ++j) a0d[j] = a0p[j];
                    #pragma unroll
                    for (int j = 0; j < 4; ++j) a1d[j] = base[a1o[j]];
                    bf16x8 a0 = dw4_to_frag(a0d[0], a0d[1], a0d[2], a0d[3]);
                    bf16x8 a1 = dw4_to_frag(a1d[0], a1d[1], a1d[2], a1d[3]);
                    f32x4 d0 = (f32x4){bb0, bb0, bb0, bb0};
                    f32x4 d1 = (f32x4){bb1, bb1, bb1, bb1};
                    d0 = __builtin_amdgcn_mfma_f32_16x16x32_bf16(a0, bfr[0][0], d0, 0, 0, 0);
                    d0 = __builtin_amdgcn_mfma_f32_16x16x32_bf16(a1, bfr[0][1], d0, 0, 0, 0);
                    d1 = __builtin_amdgcn_mfma_f32_16x16x32_bf16(a0, bfr[1][0], d1, 0, 0, 0);
                    d1 = __builtin_amdgcn_mfma_f32_16x16x32_bf16(a1, bfr[1][1], d1, 0, 0, 0);
                    #pragma unroll
                    for (int r = 0; r < 4; ++r) {
                        float h0 = fmaxf(d0[r], 0.1f * d0[r]);
                        float h1 = fmaxf(d1[r], 0.1f * d1[r]);
                        *(unsigned int*)(hp0 + (m * 64 + r) * PXS) = pack_bf2(h0, h1);
                    }
                }
                pc += 4; pr += 3;
                int w = (pc >= 20) ? 1 : 0;
                pc -= 20 * w; pr += w;
            }
        } else {
            #pragma unroll
            for (int m = 0; m < 7; ++m) {
                int mt = m * 4 + wv;
                if (mt < 25) {
                    const unsigned int* base = pxc + (pr * XS_W + pc);
                    const unsigned int* a0p  = base + kg * XS_W;   // row kg
                    unsigned int a0d[4], a1d[4];
                    #pragma unroll
                    for (int j = 0; j < 4; ++j) a0d[j] = a0p[j];
                    #pragma unroll
                    for (int j = 0; j < 4; ++j) a1d[j] = base[a1o[j]];
                    bf16x8 a0 = dw4_to_frag(a0d[0], a0d[1], a0d[2], a0d[3]);
                    bf16x8 a1 = dw4_to_frag(a1d[0], a1d[1], a1d[2], a1d[3]);
                    f32x4 d0 = (f32x4){bb0, bb0, bb0, bb0};
                    f32x4 d1 = (f32x4){bb1, bb1, bb1, bb1};
                    d0 = __builtin_amdgcn_mfma_f32_16x16x32_bf16(a0, bfr[0][0], d0, 0, 0, 0);
                    d0 = __builtin_amdgcn_mfma_f32_16x16x32_bf16(a1, bfr[0][1], d0, 0, 0, 0);
                    d1 = __builtin_amdgcn_mfma_f32_16x16x32_bf16(a0, bfr[1][0], d1, 0, 0, 0);
                    d1 = __builtin_amdgcn_mfma_f32_16x16x32_bf16(a1, bfr[1][1], d1, 0, 0, 0);
                    #pragma unroll
                    for (int r = 0; r < 4; ++r) {
                        int px = mt * 16 + kg * 4 + r;   // D row = (lane>>4)*4 + reg
                        int prr = px / HS_C, pcc = px - prr * HS_C;
                        int gy = gy0 - 2 + prr, gx = gx0 - 2 + pcc;
                        bool inb = ((unsigned)gy < HH) & ((unsigned)gx < WW);
                        float h0 = fmaxf(d0[r], 0.1f * d0[r]);
                        float h1 = fmaxf(d1[r], 0.1f * d1[r]);
                        if (!inb) { h0 = 0.f; h1 = 0.f; }
                        *(unsigned int*)(hs + px * PXS + 2 * n) = pack_bf2(h0, h1);
                    }
                }
                pc += 4; pr += 3;
                int w = (pc >= 20) ? 1 : 0;
                pc -= 20 * w; pr += w;
            }
        }
        __syncthreads();   // B: hs ready

        // ---- conv2: rolling-row MFMA GEMM (5 single-col passes), b2-init ----
        f32x4 acc[4];
        #pragma unroll
        for (int i = 0; i < 4; ++i)
            acc[i] = (f32x4){b2r[0], b2r[1], b2r[2], b2r[3]};

        conv2_pass<0>(hs, w2t, wv, n, kg, acc);
        conv2_pass<1>(hs, w2t, wv, n, kg, acc);
        conv2_pass<2>(hs, w2t, wv, n, kg, acc);
        conv2_pass<3>(hs, w2t, wv, n, kg, acc);
        conv2_pass<4>(hs, w2t, wv, n, kg, acc);

        // ---- epilogue: out = sum_f filt_f * img (img from hs stash) ----
        int o2[4];
        #pragma unroll
        for (int r2 = 0; r2 < 4; ++r2)
            o2[r2] = (int)((eop2[r2 >> 1] >> ((r2 & 1) * 16)) & 0xFFFFu);
        #pragma unroll
        for (int i = 0; i < 4; ++i) {
            int py = wv * 4 + i;
            const unsigned short* hb = hs + py * (HS_C * PXS) + n * PXS;
            float partial = 0.f;
            #pragma unroll
            for (int r2 = 0; r2 < 4; ++r2)
                partial += acc[i][r2] * *(const float*)(hb + o2[r2]);   // f>=9 term exact-zero
            partial += __shfl_down(partial, 16, 64);
            partial += __shfl_down(partial, 32, 64);
            if (lane < 16)
                out[((size_t)bb * HH + gy0 + py) * WW + gx0 + n] = partial;
        }
        __syncthreads();   // C: pxc/hs free for next batch
    }
}

extern "C" void kernel_launch(void* const* d_in, const int* in_sizes, int n_in,
                              void* d_out, int out_size, void* d_ws, size_t ws_size,
                              hipStream_t stream) {
    const float* image = (const float*)d_in[0];
    const float* refer = (const float*)d_in[1];
    const float* w1    = (const float*)d_in[2];
    const float* b1    = (const float*)d_in[3];
    const float* w2    = (const float*)d_in[4];
    const float* b2    = (const float*)d_in[5];

    unsigned short* w1c = (unsigned short*)d_ws;                   // 4 KB
    unsigned short* w2t = (unsigned short*)((char*)d_ws + 4096);   // 25.6 KB
    // ws re-poisoned before every launch -> prep must (and does) run every call

    hipLaunchKernelGGL(dynfilt_prep, dim3(32), dim3(256), 0, stream, w1, w2, w1c, w2t);

    dim3 grid(WW / TILE, HH / TILE, 1);   // persistent over batch: 1024 blocks
    hipLaunchKernelGGL(dynfilt_main, grid, dim3(256), 0, stream,
                       image, refer, b1, b2, w1c, w2t, (float*)d_out);
}

// Round 13
// 149.926 us; speedup vs baseline: 1.0635x; 1.0635x over previous
//
#include <hip/hip_runtime.h>
#include <hip/hip_bf16.h>

// DynamicFilter fused, R27 = R24 (best, 93.2us) + conflict-free epilogue
// layout (xs0f stride 39 + tuned invalid-f read slots). R25/R26 reverted.
//
// R26 post-mortem: 4 blocks/CU restored but 99.6us (vs R24 93.2) and
// conflicts 9.0e6 -> 1.115e7: hs img-stash epilogue reads conflict WORSE,
// and w1l/bfr-reload adds conv1-head latency. Both reverted. The swap did
// prove the EPILOGUE image reads are a live conflict source (+1.7e6 from a
// layout change alone). R24 epilogue bank math: bases (fy+3)*24+fx+3 mod 32
// collide 3-4-way across kg. Fix: stride 39 -> kg-step Delta = S+1 = 40 = 8
// mod 32 -> 4 bases 8-spaced; n spans 16 banks -> exactly 2 lanes/bank
// (free, m136). Invalid f>=9 slots (exact-zero terms) get offsets chosen to
// complete the 8-spaced set: eo = {f9:137, f10:138, f11:143, f12:144,
// f13:145, f14:150, f15:151}. LDS 2304+3744+32000 = 38KB -> 4 blocks/CU.
// Predict: conflicts 9.0e6 -> 6-7e6, main 93.2 -> 89-91us, VGPR ~128,
// WRITE ~9.7MB, FETCH ~33MB. If conflicts flat: epilogue not the residual
// source -> structural plateau, lock best next.
//
// d_ws: w1c bf16 [32ch][64k] @0 (k-perm layout), w2t bf16 [25tap][16f]
// [32chpos] @4096 (f>=9 zero; chpos 2i->ch i, 2i+1->ch 16+i).
// k-perm: k = s*32+kg*8+2*j+ci ; s0: tap=(kg,j); s1,kg0: tap=(4,j);
// s1,kg1: tap=(j,4); s1,kg2,j0: tap=(4,4); else invalid (w1c=0).

typedef __attribute__((ext_vector_type(8))) short bf16x8;
typedef __attribute__((ext_vector_type(4))) float f32x4;

#define HH 512
#define WW 512
#define TILE 16
#define XS_H 24
#define XS_W 24
#define XS_N (XS_H * XS_W)     // 576
#define XSF 39                 // xs0f row stride in dwords (S+1=40 === 8 mod 32)
#define HS_R 20
#define HS_C 20
#define PXS 40                 // shorts per px in hs (80B stride)

__device__ __forceinline__ unsigned short f2bf(float x) {
    union { float f; unsigned int u; } v; v.f = x;
    unsigned int u = v.u;
    u += 0x7FFFu + ((u >> 16) & 1u);   // round-to-nearest-even
    return (unsigned short)(u >> 16);
}

__device__ __forceinline__ unsigned int pack_bf2(float a, float b) {
    __hip_bfloat162 h2 = __float22bfloat162_rn(make_float2(a, b));
    union { __hip_bfloat162 h; unsigned int u; } cv; cv.h = h2;
    return cv.u;
}

__device__ __forceinline__ bf16x8 dw4_to_frag(unsigned int d0, unsigned int d1,
                                              unsigned int d2, unsigned int d3) {
    union { unsigned int u[4]; bf16x8 f; } cv;
    cv.u[0] = d0; cv.u[1] = d1; cv.u[2] = d2; cv.u[3] = d3;
    return cv.f;
}

__global__ void dynfilt_prep(const float* __restrict__ w1,
                             const float* __restrict__ w2,
                             unsigned short* __restrict__ w1c,
                             unsigned short* __restrict__ w2t)
{
    int gid = blockIdx.x * 256 + threadIdx.x;   // 8192 threads
    // w1c[ch32][k64] with k-perm (see header); invalid slots -> 0
    for (int i = gid; i < 32 * 64; i += 8192) {
        int ch = i >> 6, k = i & 63;
        int s = (k >> 5) & 1, kg = (k >> 3) & 3, j = (k >> 1) & 3, ci = k & 1;
        int tap = 0; bool val = true;
        if (!s)            tap = kg * 5 + j;        // rows 0-3, cols 0-3
        else if (kg == 0)  tap = 20 + j;            // row 4, cols 0-3
        else if (kg == 1)  tap = j * 5 + 4;         // col 4, rows 0-3
        else if (kg == 2) { tap = 24; val = (j == 0); }   // corner (4,4)
        else               val = false;
        w1c[i] = val ? f2bf(w1[(ch * 2 + ci) * 25 + tap]) : (unsigned short)0;
    }
    // w2t[tap25][f16][chpos32]: chpos 2i -> ch i, 2i+1 -> ch 16+i; f>=9 zero
    for (int i = gid; i < 25 * 16 * 32; i += 8192) {
        int p = i & 31;
        int f = (i >> 5) & 15;
        int tap = i >> 9;   // 0..24
        int ch = (p & 1) * 16 + (p >> 1);
        w2t[i] = (f < 9) ? f2bf(w2[(f * 32 + ch) * 25 + tap]) : (unsigned short)0;
    }
}

// conv2 pass over single tap-col TC0: rolling 4-row B-frag buffer.
// B-frag(row = wv*4 + i + tr, col = n + TC0) shared across (i,tr) with equal
// i+tr; rows rotate through R[.&3]. All indices compile-time after unroll.
template<int TC0>
__device__ __forceinline__ void conv2_pass(const unsigned short* hsp,
                                           const unsigned short* __restrict__ w2t,
                                           int wv, int n, int kg, f32x4* acc) {
    bf16x8 R[4];
    #pragma unroll
    for (int q = 0; q < 4; ++q)
        R[q] = *(const bf16x8*)(hsp + ((wv * 4 + q) * HS_C + n + TC0) * PXS + kg * 8);
    #pragma unroll
    for (int tr = 0; tr < 5; ++tr) {
        bf16x8 afr = *(const bf16x8*)(w2t + ((tr * 5 + TC0) * 16 + n) * 32 + kg * 8);
        #pragma unroll
        for (int i = 0; i < 4; ++i)
            acc[i] = __builtin_amdgcn_mfma_f32_16x16x32_bf16(afr, R[(tr + i) & 3], acc[i], 0, 0, 0);
        if (tr < 4)
            R[tr & 3] = *(const bf16x8*)(hsp + ((wv * 4 + tr + 4) * HS_C + n + TC0) * PXS + kg * 8);
    }
}

__global__
__attribute__((amdgpu_flat_work_group_size(256, 256), amdgpu_waves_per_eu(2)))
void dynfilt_main(const float* __restrict__ image,
                  const float* __restrict__ refer,
                  const float* __restrict__ b1,
                  const float* __restrict__ b2,
                  const unsigned short* __restrict__ w1c,
                  const unsigned short* __restrict__ w2t,
                  float* __restrict__ out)
{
    __shared__ float xs0f[XS_H * XSF];          // image fp32, stride-39 rows
    __shared__ unsigned int pxc[XS_N];          // packed (bf16 img | bf16 ref)
    __shared__ __align__(16) unsigned short hs[HS_R * HS_C * PXS];

    const int t   = threadIdx.x;
    const int gx0 = blockIdx.x * TILE;
    const int gy0 = blockIdx.y * TILE;

    // whole halo (rows gy0-4..+19, cols gx0-4..+19) in-bounds?
    const bool interior = (gy0 >= 4) && (gy0 + XS_H - 4 <= HH) &&
                          (gx0 >= 4) && (gx0 + XS_W - 4 <= WW);

    // ---- batch-invariant staging offsets (sentinel -1 = skip) ----
    int soff[3];
    #pragma unroll
    for (int k = 0; k < 3; ++k) {
        int idx = t + k * 256;
        int r = idx / XS_W, c = idx - (idx / XS_W) * XS_W;
        int gy = gy0 - 4 + r, gx = gx0 - 4 + c;
        bool inb = (idx < XS_N) & ((unsigned)gy < HH) & ((unsigned)gx < WW);
        soff[k] = inb ? (gy * WW + gx) : -1;
    }

    const int lane = t & 63;
    const int wv   = t >> 6;
    const int n    = lane & 15;
    const int kg   = lane >> 4;

    // ---- conv1 B-frags: loaded ONCE, carried (w1c L1-hot) ----
    bf16x8 bfr[2][2];
    #pragma unroll
    for (int nt = 0; nt < 2; ++nt)
        #pragma unroll
        for (int s = 0; s < 2; ++s)
            bfr[nt][s] = *(const bf16x8*)(w1c + (nt * 16 + n) * 64 + s * 32 + kg * 8);

    // ---- a1 gather offsets (k-perm layout), packed 4x8bit; invalid -> 0
    //      (broadcast read, zero weight in w1c makes the product exact-0) ----
    unsigned int a1opk = 0;
    #pragma unroll
    for (int j = 0; j < 4; ++j) {
        int o = (kg == 0) ? (4 * XS_W + j)                  // row 4, col j
              : (kg == 1) ? (j * XS_W + 4)                  // row j, col 4
              : (kg == 2 && j == 0) ? (4 * XS_W + 4) : 0;   // corner / dummy
        a1opk |= (unsigned)o << (8 * j);
    }

    // px = mt*16 + n raster start (pr0,pc0) over 20-wide h grid
    int px0 = wv * 16 + n;
    const int pr0 = px0 / 20, pc0 = px0 - (px0 / 20) * 20;

    const float bb0 = b1[n], bb1 = b1[16 + n];

    // ---- conv2 / epilogue constants (once); eo packed 4x8bit.
    //      Valid f: eo = (fy+3)*39 + fx+3. Invalid f>=9: bank-filler slots
    //      completing the 8-spaced base set (term is exact-zero, acc=0). ----
    float b2r[4];
    unsigned int eopk = 0;
    #pragma unroll
    for (int r2 = 0; r2 < 4; ++r2) {
        int f = kg * 4 + r2;
        b2r[r2] = (f < 9) ? b2[f] : 0.f;
        unsigned int e;
        if (f < 9) {
            int fy = f / 3, fx = f - fy * 3;
            e = (unsigned)((fy + 3) * XSF + fx + 3);   // 120..200
        } else {
            // f: 9,10,11,12,13,14,15 -> 137,138,143,144,145,150,151
            const unsigned int fill[7] = {137u, 138u, 143u, 144u, 145u, 150u, 151u};
            e = fill[f - 9];
        }
        eopk |= e << (8 * r2);
    }

    // ---- prefetch batch 0 halo into regs ----
    float pvI[3], pvR[3];
    #pragma unroll
    for (int k = 0; k < 3; ++k) {
        pvI[k] = 0.f; pvR[k] = 0.f;
        if (soff[k] >= 0) {
            pvI[k] = image[soff[k]];
            pvR[k] = refer[soff[k]];
        }
    }

    #pragma unroll 1
    for (int bb = 0; bb < 8; ++bb) {
        // ---- stage write from prefetch regs ----
        #pragma unroll
        for (int k = 0; k < 3; ++k) {
            int idx = t + k * 256;
            if (idx < XS_N) {
                int r = idx / XS_W, c = idx - (idx / XS_W) * XS_W;
                xs0f[r * XSF + c] = pvI[k];
                pxc[idx] = pack_bf2(pvI[k], pvR[k]);
            }
        }
        __syncthreads();   // A: xs0f/pxc ready

        // ---- issue next batch's prefetch (hides under conv1+conv2) ----
        if (bb < 7) {
            const float* ibn = image + (size_t)(bb + 1) * (HH * WW);
            const float* rbn = refer + (size_t)(bb + 1) * (HH * WW);
            #pragma unroll
            for (int k = 0; k < 3; ++k) {
                pvI[k] = 0.f; pvR[k] = 0.f;
                if (soff[k] >= 0) {
                    pvI[k] = ibn[soff[k]];
                    pvR[k] = rbn[soff[k]];
                }
            }
        }

        // ---- unpack a1 offsets (conv1-local regs) ----
        int a1o[4];
        #pragma unroll
        for (int j = 0; j < 4; ++j)
            a1o[j] = (int)((a1opk >> (8 * j)) & 0xFFu);

        // ---- conv1 GEMM + fused leaky+pack write to hs ----
        int pr = pr0, pc = pc0;
        if (interior) {
            unsigned short* hp0 = hs + (wv * 16 + kg * 4) * PXS + 2 * n;
            #pragma unroll
            for (int m = 0; m < 7; ++m) {
                int mt = m * 4 + wv;
                if (mt < 25) {   // wave-uniform guard
                    const unsigned int* base = pxc + (pr * XS_W + pc);
                    const unsigned int* a0p  = base + kg * XS_W;   // row kg
                    unsigned int a0d[4], a1d[4];
                    #pragma unroll
                    for (int j = 0; j < 4; ++j) a0d[j] = a0p[j];
                    #pragma unroll
                    for (int j = 0; j < 4; ++j) a1d[j] = base[a1o[j]];
                    bf16x8 a0 = dw4_to_frag(a0d[0], a0d[1], a0d[2], a0d[3]);
                    bf16x8 a1 = dw4_to_frag(a1d[0], a1d[1], a1d[2], a1d[3]);
                    f32x4 d0 = (f32x4){bb0, bb0, bb0, bb0};
                    f32x4 d1 = (f32x4){bb1, bb1, bb1, bb1};
                    d0 = __builtin_amdgcn_mfma_f32_16x16x32_bf16(a0, bfr[0][0], d0, 0, 0, 0);
                    d0 = __builtin_amdgcn_mfma_f32_16x16x32_bf16(a1, bfr[0][1], d0, 0, 0, 0);
                    d1 = __builtin_amdgcn_mfma_f32_16x16x32_bf16(a0, bfr[1][0], d1, 0, 0, 0);
                    d1 = __builtin_amdgcn_mfma_f32_16x16x32_bf16(a1, bfr[1][1], d1, 0, 0, 0);
                    #pragma unroll
                    for (int r = 0; r < 4; ++r) {
                        float h0 = fmaxf(d0[r], 0.1f * d0[r]);
                        float h1 = fmaxf(d1[r], 0.1f * d1[r]);
                        *(unsigned int*)(hp0 + (m * 64 + r) * PXS) = pack_bf2(h0, h1);
                    }
                }
                pc += 4; pr += 3;
                int w = (pc >= 20) ? 1 : 0;
                pc -= 20 * w; pr += w;
            }
        } else {
            #pragma unroll
            for (int m = 0; m < 7; ++m) {
                int mt = m * 4 + wv;
                if (mt < 25) {
                    const unsigned int* base = pxc + (pr * XS_W + pc);
                    const unsigned int* a0p  = base + kg * XS_W;   // row kg
                    unsigned int a0d[4], a1d[4];
                    #pragma unroll
                    for (int j = 0; j < 4; ++j) a0d[j] = a0p[j];
                    #pragma unroll
                    for (int j = 0; j < 4; ++j) a1d[j] = base[a1o[j]];
                    bf16x8 a0 = dw4_to_frag(a0d[0], a0d[1], a0d[2], a0d[3]);
                    bf16x8 a1 = dw4_to_frag(a1d[0], a1d[1], a1d[2], a1d[3]);
                    f32x4 d0 = (f32x4){bb0, bb0, bb0, bb0};
                    f32x4 d1 = (f32x4){bb1, bb1, bb1, bb1};
                    d0 = __builtin_amdgcn_mfma_f32_16x16x32_bf16(a0, bfr[0][0], d0, 0, 0, 0);
                    d0 = __builtin_amdgcn_mfma_f32_16x16x32_bf16(a1, bfr[0][1], d0, 0, 0, 0);
                    d1 = __builtin_amdgcn_mfma_f32_16x16x32_bf16(a0, bfr[1][0], d1, 0, 0, 0);
                    d1 = __builtin_amdgcn_mfma_f32_16x16x32_bf16(a1, bfr[1][1], d1, 0, 0, 0);
                    #pragma unroll
                    for (int r = 0; r < 4; ++r) {
                        int px = mt * 16 + kg * 4 + r;   // D row = (lane>>4)*4 + reg
                        int prr = px / HS_C, pcc = px - prr * HS_C;
                        int gy = gy0 - 2 + prr, gx = gx0 - 2 + pcc;
                        bool inb = ((unsigned)gy < HH) & ((unsigned)gx < WW);
                        float h0 = fmaxf(d0[r], 0.1f * d0[r]);
                        float h1 = fmaxf(d1[r], 0.1f * d1[r]);
                        if (!inb) { h0 = 0.f; h1 = 0.f; }
                        *(unsigned int*)(hs + px * PXS + 2 * n) = pack_bf2(h0, h1);
                    }
                }
                pc += 4; pr += 3;
                int w = (pc >= 20) ? 1 : 0;
                pc -= 20 * w; pr += w;
            }
        }
        __syncthreads();   // B: hs ready

        // ---- conv2: rolling-row MFMA GEMM (5 single-col passes), b2-init ----
        f32x4 acc[4];
        #pragma unroll
        for (int i = 0; i < 4; ++i)
            acc[i] = (f32x4){b2r[0], b2r[1], b2r[2], b2r[3]};

        conv2_pass<0>(hs, w2t, wv, n, kg, acc);
        conv2_pass<1>(hs, w2t, wv, n, kg, acc);
        conv2_pass<2>(hs, w2t, wv, n, kg, acc);
        conv2_pass<3>(hs, w2t, wv, n, kg, acc);
        conv2_pass<4>(hs, w2t, wv, n, kg, acc);

        // ---- epilogue: out = sum_f filt_f * image[y+fy-1][x+fx-1] ----
        int eo[4];
        #pragma unroll
        for (int r2 = 0; r2 < 4; ++r2)
            eo[r2] = (int)((eopk >> (8 * r2)) & 0xFFu);
        #pragma unroll
        for (int i = 0; i < 4; ++i) {
            int py = wv * 4 + i;
            const float* xb = xs0f + py * XSF + n;
            float partial = 0.f;
            #pragma unroll
            for (int r2 = 0; r2 < 4; ++r2)
                partial += acc[i][r2] * xb[eo[r2]];   // f>=9 term exact-zero
            partial += __shfl_down(partial, 16, 64);
            partial += __shfl_down(partial, 32, 64);
            if (lane < 16)
                out[((size_t)bb * HH + gy0 + py) * WW + gx0 + n] = partial;
        }
        __syncthreads();   // C: xs0f/pxc/hs free for next batch
    }
}

extern "C" void kernel_launch(void* const* d_in, const int* in_sizes, int n_in,
                              void* d_out, int out_size, void* d_ws, size_t ws_size,
                              hipStream_t stream) {
    const float* image = (const float*)d_in[0];
    const float* refer = (const float*)d_in[1];
    const float* w1    = (const float*)d_in[2];
    const float* b1    = (const float*)d_in[3];
    const float* w2    = (const float*)d_in[4];
    const float* b2    = (const float*)d_in[5];

    unsigned short* w1c = (unsigned short*)d_ws;                   // 4 KB
    unsigned short* w2t = (unsigned short*)((char*)d_ws + 4096);   // 25.6 KB
    // ws re-poisoned before every launch -> prep must (and does) run every call

    hipLaunchKernelGGL(dynfilt_prep, dim3(32), dim3(256), 0, stream, w1, w2, w1c, w2t);

    dim3 grid(WW / TILE, HH / TILE, 1);   // persistent over batch: 1024 blocks
    hipLaunchKernelGGL(dynfilt_main, grid, dim3(256), 0, stream,
                       image, refer, b1, b2, w1c, w2t, (float*)d_out);
}

// Round 14
// 146.741 us; speedup vs baseline: 1.0866x; 1.0217x over previous
//
#include <hip/hip_runtime.h>
#include <hip/hip_bf16.h>

// DynamicFilter fused, R28 = R27 (best, 88.2us) with the epilogue fill table
// replaced by arithmetic — removes runtime-indexed local array (scratch).
//
// R27 post-mortem: helped 93.2 -> 88.2us; epilogue stride-39 layout verified
// (all four read instrs land exactly 2 lanes/bank). But WRITE rose 9.7 ->
// 13.7MB: `const uint fill[7]` indexed by f-9 (f = kg*4+r2, kg RUNTIME) ->
// scratch (rule #20). R28: e = 137 + idx + 4*((idx+1)/3), idx = f-9 —
// reproduces {137,138,143,144,145,150,151} exactly, no array. Nothing else
// changed (isolates the scratch variable).
// Predict: WRITE 13.7 -> 8.2-9.7MB, main 88.2 -> 83-86us, VGPR <=128,
// conflicts ~8.7e6 / FETCH ~33MB unchanged. If lands: remaining headroom
// thin -> final structural swing or lock-in next.
//
// d_ws: w1c bf16 [32ch][64k] @0 (k-perm layout), w2t bf16 [25tap][16f]
// [32chpos] @4096 (f>=9 zero; chpos 2i->ch i, 2i+1->ch 16+i).
// k-perm: k = s*32+kg*8+2*j+ci ; s0: tap=(kg,j); s1,kg0: tap=(4,j);
// s1,kg1: tap=(j,4); s1,kg2,j0: tap=(4,4); else invalid (w1c=0).

typedef __attribute__((ext_vector_type(8))) short bf16x8;
typedef __attribute__((ext_vector_type(4))) float f32x4;

#define HH 512
#define WW 512
#define TILE 16
#define XS_H 24
#define XS_W 24
#define XS_N (XS_H * XS_W)     // 576
#define XSF 39                 // xs0f row stride in dwords (S+1=40 === 8 mod 32)
#define HS_R 20
#define HS_C 20
#define PXS 40                 // shorts per px in hs (80B stride)

__device__ __forceinline__ unsigned short f2bf(float x) {
    union { float f; unsigned int u; } v; v.f = x;
    unsigned int u = v.u;
    u += 0x7FFFu + ((u >> 16) & 1u);   // round-to-nearest-even
    return (unsigned short)(u >> 16);
}

__device__ __forceinline__ unsigned int pack_bf2(float a, float b) {
    __hip_bfloat162 h2 = __float22bfloat162_rn(make_float2(a, b));
    union { __hip_bfloat162 h; unsigned int u; } cv; cv.h = h2;
    return cv.u;
}

__device__ __forceinline__ bf16x8 dw4_to_frag(unsigned int d0, unsigned int d1,
                                              unsigned int d2, unsigned int d3) {
    union { unsigned int u[4]; bf16x8 f; } cv;
    cv.u[0] = d0; cv.u[1] = d1; cv.u[2] = d2; cv.u[3] = d3;
    return cv.f;
}

__global__ void dynfilt_prep(const float* __restrict__ w1,
                             const float* __restrict__ w2,
                             unsigned short* __restrict__ w1c,
                             unsigned short* __restrict__ w2t)
{
    int gid = blockIdx.x * 256 + threadIdx.x;   // 8192 threads
    // w1c[ch32][k64] with k-perm (see header); invalid slots -> 0
    for (int i = gid; i < 32 * 64; i += 8192) {
        int ch = i >> 6, k = i & 63;
        int s = (k >> 5) & 1, kg = (k >> 3) & 3, j = (k >> 1) & 3, ci = k & 1;
        int tap = 0; bool val = true;
        if (!s)            tap = kg * 5 + j;        // rows 0-3, cols 0-3
        else if (kg == 0)  tap = 20 + j;            // row 4, cols 0-3
        else if (kg == 1)  tap = j * 5 + 4;         // col 4, rows 0-3
        else if (kg == 2) { tap = 24; val = (j == 0); }   // corner (4,4)
        else               val = false;
        w1c[i] = val ? f2bf(w1[(ch * 2 + ci) * 25 + tap]) : (unsigned short)0;
    }
    // w2t[tap25][f16][chpos32]: chpos 2i -> ch i, 2i+1 -> ch 16+i; f>=9 zero
    for (int i = gid; i < 25 * 16 * 32; i += 8192) {
        int p = i & 31;
        int f = (i >> 5) & 15;
        int tap = i >> 9;   // 0..24
        int ch = (p & 1) * 16 + (p >> 1);
        w2t[i] = (f < 9) ? f2bf(w2[(f * 32 + ch) * 25 + tap]) : (unsigned short)0;
    }
}

// conv2 pass over single tap-col TC0: rolling 4-row B-frag buffer.
// B-frag(row = wv*4 + i + tr, col = n + TC0) shared across (i,tr) with equal
// i+tr; rows rotate through R[.&3]. All indices compile-time after unroll.
template<int TC0>
__device__ __forceinline__ void conv2_pass(const unsigned short* hsp,
                                           const unsigned short* __restrict__ w2t,
                                           int wv, int n, int kg, f32x4* acc) {
    bf16x8 R[4];
    #pragma unroll
    for (int q = 0; q < 4; ++q)
        R[q] = *(const bf16x8*)(hsp + ((wv * 4 + q) * HS_C + n + TC0) * PXS + kg * 8);
    #pragma unroll
    for (int tr = 0; tr < 5; ++tr) {
        bf16x8 afr = *(const bf16x8*)(w2t + ((tr * 5 + TC0) * 16 + n) * 32 + kg * 8);
        #pragma unroll
        for (int i = 0; i < 4; ++i)
            acc[i] = __builtin_amdgcn_mfma_f32_16x16x32_bf16(afr, R[(tr + i) & 3], acc[i], 0, 0, 0);
        if (tr < 4)
            R[tr & 3] = *(const bf16x8*)(hsp + ((wv * 4 + tr + 4) * HS_C + n + TC0) * PXS + kg * 8);
    }
}

__global__
__attribute__((amdgpu_flat_work_group_size(256, 256), amdgpu_waves_per_eu(2)))
void dynfilt_main(const float* __restrict__ image,
                  const float* __restrict__ refer,
                  const float* __restrict__ b1,
                  const float* __restrict__ b2,
                  const unsigned short* __restrict__ w1c,
                  const unsigned short* __restrict__ w2t,
                  float* __restrict__ out)
{
    __shared__ float xs0f[XS_H * XSF];          // image fp32, stride-39 rows
    __shared__ unsigned int pxc[XS_N];          // packed (bf16 img | bf16 ref)
    __shared__ __align__(16) unsigned short hs[HS_R * HS_C * PXS];

    const int t   = threadIdx.x;
    const int gx0 = blockIdx.x * TILE;
    const int gy0 = blockIdx.y * TILE;

    // whole halo (rows gy0-4..+19, cols gx0-4..+19) in-bounds?
    const bool interior = (gy0 >= 4) && (gy0 + XS_H - 4 <= HH) &&
                          (gx0 >= 4) && (gx0 + XS_W - 4 <= WW);

    // ---- batch-invariant staging offsets (sentinel -1 = skip) ----
    int soff[3];
    #pragma unroll
    for (int k = 0; k < 3; ++k) {
        int idx = t + k * 256;
        int r = idx / XS_W, c = idx - (idx / XS_W) * XS_W;
        int gy = gy0 - 4 + r, gx = gx0 - 4 + c;
        bool inb = (idx < XS_N) & ((unsigned)gy < HH) & ((unsigned)gx < WW);
        soff[k] = inb ? (gy * WW + gx) : -1;
    }

    const int lane = t & 63;
    const int wv   = t >> 6;
    const int n    = lane & 15;
    const int kg   = lane >> 4;

    // ---- conv1 B-frags: loaded ONCE, carried (w1c L1-hot) ----
    bf16x8 bfr[2][2];
    #pragma unroll
    for (int nt = 0; nt < 2; ++nt)
        #pragma unroll
        for (int s = 0; s < 2; ++s)
            bfr[nt][s] = *(const bf16x8*)(w1c + (nt * 16 + n) * 64 + s * 32 + kg * 8);

    // ---- a1 gather offsets (k-perm layout), packed 4x8bit; invalid -> 0
    //      (broadcast read, zero weight in w1c makes the product exact-0) ----
    unsigned int a1opk = 0;
    #pragma unroll
    for (int j = 0; j < 4; ++j) {
        int o = (kg == 0) ? (4 * XS_W + j)                  // row 4, col j
              : (kg == 1) ? (j * XS_W + 4)                  // row j, col 4
              : (kg == 2 && j == 0) ? (4 * XS_W + 4) : 0;   // corner / dummy
        a1opk |= (unsigned)o << (8 * j);
    }

    // px = mt*16 + n raster start (pr0,pc0) over 20-wide h grid
    int px0 = wv * 16 + n;
    const int pr0 = px0 / 20, pc0 = px0 - (px0 / 20) * 20;

    const float bb0 = b1[n], bb1 = b1[16 + n];

    // ---- conv2 / epilogue constants (once); eo packed 4x8bit.
    //      Valid f: eo = (fy+3)*39 + fx+3. Invalid f>=9: bank-filler slots
    //      computed ARITHMETICALLY (no runtime-indexed array -> no scratch):
    //      idx = f-9 -> e = 137 + idx + 4*((idx+1)/3) = {137,138,143,144,
    //      145,150,151}. All 4 read instrs land exactly 2 lanes/bank. ----
    float b2r[4];
    unsigned int eopk = 0;
    #pragma unroll
    for (int r2 = 0; r2 < 4; ++r2) {
        int f = kg * 4 + r2;
        b2r[r2] = (f < 9) ? b2[f] : 0.f;
        unsigned int e;
        if (f < 9) {
            int fy = f / 3, fx = f - fy * 3;
            e = (unsigned)((fy + 3) * XSF + fx + 3);   // 120..200
        } else {
            int idx = f - 9;                           // 0..6
            e = 137u + (unsigned)idx + 4u * (unsigned)((idx + 1) / 3);
        }
        eopk |= e << (8 * r2);
    }

    // ---- prefetch batch 0 halo into regs ----
    float pvI[3], pvR[3];
    #pragma unroll
    for (int k = 0; k < 3; ++k) {
        pvI[k] = 0.f; pvR[k] = 0.f;
        if (soff[k] >= 0) {
            pvI[k] = image[soff[k]];
            pvR[k] = refer[soff[k]];
        }
    }

    #pragma unroll 1
    for (int bb = 0; bb < 8; ++bb) {
        // ---- stage write from prefetch regs ----
        #pragma unroll
        for (int k = 0; k < 3; ++k) {
            int idx = t + k * 256;
            if (idx < XS_N) {
                int r = idx / XS_W, c = idx - (idx / XS_W) * XS_W;
                xs0f[r * XSF + c] = pvI[k];
                pxc[idx] = pack_bf2(pvI[k], pvR[k]);
            }
        }
        __syncthreads();   // A: xs0f/pxc ready

        // ---- issue next batch's prefetch (hides under conv1+conv2) ----
        if (bb < 7) {
            const float* ibn = image + (size_t)(bb + 1) * (HH * WW);
            const float* rbn = refer + (size_t)(bb + 1) * (HH * WW);
            #pragma unroll
            for (int k = 0; k < 3; ++k) {
                pvI[k] = 0.f; pvR[k] = 0.f;
                if (soff[k] >= 0) {
                    pvI[k] = ibn[soff[k]];
                    pvR[k] = rbn[soff[k]];
                }
            }
        }

        // ---- unpack a1 offsets (conv1-local regs) ----
        int a1o[4];
        #pragma unroll
        for (int j = 0; j < 4; ++j)
            a1o[j] = (int)((a1opk >> (8 * j)) & 0xFFu);

        // ---- conv1 GEMM + fused leaky+pack write to hs ----
        int pr = pr0, pc = pc0;
        if (interior) {
            unsigned short* hp0 = hs + (wv * 16 + kg * 4) * PXS + 2 * n;
            #pragma unroll
            for (int m = 0; m < 7; ++m) {
                int mt = m * 4 + wv;
                if (mt < 25) {   // wave-uniform guard
                    const unsigned int* base = pxc + (pr * XS_W + pc);
                    const unsigned int* a0p  = base + kg * XS_W;   // row kg
                    unsigned int a0d[4], a1d[4];
                    #pragma unroll
                    for (int j = 0; j < 4; ++j) a0d[j] = a0p[j];
                    #pragma unroll
                    for (int j = 0; j < 4; ++j) a1d[j] = base[a1o[j]];
                    bf16x8 a0 = dw4_to_frag(a0d[0], a0d[1], a0d[2], a0d[3]);
                    bf16x8 a1 = dw4_to_frag(a1d[0], a1d[1], a1d[2], a1d[3]);
                    f32x4 d0 = (f32x4){bb0, bb0, bb0, bb0};
                    f32x4 d1 = (f32x4){bb1, bb1, bb1, bb1};
                    d0 = __builtin_amdgcn_mfma_f32_16x16x32_bf16(a0, bfr[0][0], d0, 0, 0, 0);
                    d0 = __builtin_amdgcn_mfma_f32_16x16x32_bf16(a1, bfr[0][1], d0, 0, 0, 0);
                    d1 = __builtin_amdgcn_mfma_f32_16x16x32_bf16(a0, bfr[1][0], d1, 0, 0, 0);
                    d1 = __builtin_amdgcn_mfma_f32_16x16x32_bf16(a1, bfr[1][1], d1, 0, 0, 0);
                    #pragma unroll
                    for (int r = 0; r < 4; ++r) {
                        float h0 = fmaxf(d0[r], 0.1f * d0[r]);
                        float h1 = fmaxf(d1[r], 0.1f * d1[r]);
                        *(unsigned int*)(hp0 + (m * 64 + r) * PXS) = pack_bf2(h0, h1);
                    }
                }
                pc += 4; pr += 3;
                int w = (pc >= 20) ? 1 : 0;
                pc -= 20 * w; pr += w;
            }
        } else {
            #pragma unroll
            for (int m = 0; m < 7; ++m) {
                int mt = m * 4 + wv;
                if (mt < 25) {
                    const unsigned int* base = pxc + (pr * XS_W + pc);
                    const unsigned int* a0p  = base + kg * XS_W;   // row kg
                    unsigned int a0d[4], a1d[4];
                    #pragma unroll
                    for (int j = 0; j < 4; ++j) a0d[j] = a0p[j];
                    #pragma unroll
                    for (int j = 0; j < 4; ++j) a1d[j] = base[a1o[j]];
                    bf16x8 a0 = dw4_to_frag(a0d[0], a0d[1], a0d[2], a0d[3]);
                    bf16x8 a1 = dw4_to_frag(a1d[0], a1d[1], a1d[2], a1d[3]);
                    f32x4 d0 = (f32x4){bb0, bb0, bb0, bb0};
                    f32x4 d1 = (f32x4){bb1, bb1, bb1, bb1};
                    d0 = __builtin_amdgcn_mfma_f32_16x16x32_bf16(a0, bfr[0][0], d0, 0, 0, 0);
                    d0 = __builtin_amdgcn_mfma_f32_16x16x32_bf16(a1, bfr[0][1], d0, 0, 0, 0);
                    d1 = __builtin_amdgcn_mfma_f32_16x16x32_bf16(a0, bfr[1][0], d1, 0, 0, 0);
                    d1 = __builtin_amdgcn_mfma_f32_16x16x32_bf16(a1, bfr[1][1], d1, 0, 0, 0);
                    #pragma unroll
                    for (int r = 0; r < 4; ++r) {
                        int px = mt * 16 + kg * 4 + r;   // D row = (lane>>4)*4 + reg
                        int prr = px / HS_C, pcc = px - prr * HS_C;
                        int gy = gy0 - 2 + prr, gx = gx0 - 2 + pcc;
                        bool inb = ((unsigned)gy < HH) & ((unsigned)gx < WW);
                        float h0 = fmaxf(d0[r], 0.1f * d0[r]);
                        float h1 = fmaxf(d1[r], 0.1f * d1[r]);
                        if (!inb) { h0 = 0.f; h1 = 0.f; }
                        *(unsigned int*)(hs + px * PXS + 2 * n) = pack_bf2(h0, h1);
                    }
                }
                pc += 4; pr += 3;
                int w = (pc >= 20) ? 1 : 0;
                pc -= 20 * w; pr += w;
            }
        }
        __syncthreads();   // B: hs ready

        // ---- conv2: rolling-row MFMA GEMM (5 single-col passes), b2-init ----
        f32x4 acc[4];
        #pragma unroll
        for (int i = 0; i < 4; ++i)
            acc[i] = (f32x4){b2r[0], b2r[1], b2r[2], b2r[3]};

        conv2_pass<0>(hs, w2t, wv, n, kg, acc);
        conv2_pass<1>(hs, w2t, wv, n, kg, acc);
        conv2_pass<2>(hs, w2t, wv, n, kg, acc);
        conv2_pass<3>(hs, w2t, wv, n, kg, acc);
        conv2_pass<4>(hs, w2t, wv, n, kg, acc);

        // ---- epilogue: out = sum_f filt_f * image[y+fy-1][x+fx-1] ----
        int eo[4];
        #pragma unroll
        for (int r2 = 0; r2 < 4; ++r2)
            eo[r2] = (int)((eopk >> (8 * r2)) & 0xFFu);
        #pragma unroll
        for (int i = 0; i < 4; ++i) {
            int py = wv * 4 + i;
            const float* xb = xs0f + py * XSF + n;
            float partial = 0.f;
            #pragma unroll
            for (int r2 = 0; r2 < 4; ++r2)
                partial += acc[i][r2] * xb[eo[r2]];   // f>=9 term exact-zero
            partial += __shfl_down(partial, 16, 64);
            partial += __shfl_down(partial, 32, 64);
            if (lane < 16)
                out[((size_t)bb * HH + gy0 + py) * WW + gx0 + n] = partial;
        }
        __syncthreads();   // C: xs0f/pxc/hs free for next batch
    }
}

extern "C" void kernel_launch(void* const* d_in, const int* in_sizes, int n_in,
                              void* d_out, int out_size, void* d_ws, size_t ws_size,
                              hipStream_t stream) {
    const float* image = (const float*)d_in[0];
    const float* refer = (const float*)d_in[1];
    const float* w1    = (const float*)d_in[2];
    const float* b1    = (const float*)d_in[3];
    const float* w2    = (const float*)d_in[4];
    const float* b2    = (const float*)d_in[5];

    unsigned short* w1c = (unsigned short*)d_ws;                   // 4 KB
    unsigned short* w2t = (unsigned short*)((char*)d_ws + 4096);   // 25.6 KB
    // ws re-poisoned before every launch -> prep must (and does) run every call

    hipLaunchKernelGGL(dynfilt_prep, dim3(32), dim3(256), 0, stream, w1, w2, w1c, w2t);

    dim3 grid(WW / TILE, HH / TILE, 1);   // persistent over batch: 1024 blocks
    hipLaunchKernelGGL(dynfilt_main, grid, dim3(256), 0, stream,
                       image, refer, b1, b2, w1c, w2t, (float*)d_out);
}

// Round 15
// 138.181 us; speedup vs baseline: 1.1539x; 1.0620x over previous
//
#include <hip/hip_runtime.h>
#include <hip/hip_bf16.h>

// DynamicFilter fused, R29 = R28 (best, 86.5us) with conv1 interior/boundary
// paths UNIFIED via a precomputed 28-bit OOB mask.
//
// R28 post-mortem: 88.2 -> 86.5us but WRITE still 13.6MB (~5.4MB scratch),
// VGPR pinned 128 -> allocator over budget at the conv1-pipeline/conv2 peak;
// fill-table wasn't the spill source. Occupancy decode: VGPR_Count excludes
// AGPRs; 128 + acc AGPRs > 128-total ladder -> hard 2 waves/SIMD (= the ~20%
// plateau). Remaining fat with a mechanism: the duplicated if(interior)/else
// conv1 bodies (regalloc covers max of both; else path has 28 divs/iter).
// hs write addr is affine in (m,r) for BOTH paths (px = m*64+wv*16+kg*4+r);
// boundary differs only by OOB-zeroing. R29 unifies: batch-invariant 28-bit
// mask/thread (divs once per block), affine addressing everywhere, h zeroed
// by mask bit. Halves conv1 code, removes else-path peak.
// Predict: VGPR 112-124 unpinned, WRITE -> 8.2-9MB, main 86.5 -> 83-85us,
// conflicts/FETCH unchanged. If VGPR still 128: cap m-loop unroll next
// (final); if neutral: lock best and conclude.
//
// d_ws: w1c bf16 [32ch][64k] @0 (k-perm layout), w2t bf16 [25tap][16f]
// [32chpos] @4096 (f>=9 zero; chpos 2i->ch i, 2i+1->ch 16+i).
// k-perm: k = s*32+kg*8+2*j+ci ; s0: tap=(kg,j); s1,kg0: tap=(4,j);
// s1,kg1: tap=(j,4); s1,kg2,j0: tap=(4,4); else invalid (w1c=0).

typedef __attribute__((ext_vector_type(8))) short bf16x8;
typedef __attribute__((ext_vector_type(4))) float f32x4;

#define HH 512
#define WW 512
#define TILE 16
#define XS_H 24
#define XS_W 24
#define XS_N (XS_H * XS_W)     // 576
#define XSF 39                 // xs0f row stride in dwords (S+1=40 === 8 mod 32)
#define HS_R 20
#define HS_C 20
#define PXS 40                 // shorts per px in hs (80B stride)

__device__ __forceinline__ unsigned short f2bf(float x) {
    union { float f; unsigned int u; } v; v.f = x;
    unsigned int u = v.u;
    u += 0x7FFFu + ((u >> 16) & 1u);   // round-to-nearest-even
    return (unsigned short)(u >> 16);
}

__device__ __forceinline__ unsigned int pack_bf2(float a, float b) {
    __hip_bfloat162 h2 = __float22bfloat162_rn(make_float2(a, b));
    union { __hip_bfloat162 h; unsigned int u; } cv; cv.h = h2;
    return cv.u;
}

__device__ __forceinline__ bf16x8 dw4_to_frag(unsigned int d0, unsigned int d1,
                                              unsigned int d2, unsigned int d3) {
    union { unsigned int u[4]; bf16x8 f; } cv;
    cv.u[0] = d0; cv.u[1] = d1; cv.u[2] = d2; cv.u[3] = d3;
    return cv.f;
}

__global__ void dynfilt_prep(const float* __restrict__ w1,
                             const float* __restrict__ w2,
                             unsigned short* __restrict__ w1c,
                             unsigned short* __restrict__ w2t)
{
    int gid = blockIdx.x * 256 + threadIdx.x;   // 8192 threads
    // w1c[ch32][k64] with k-perm (see header); invalid slots -> 0
    for (int i = gid; i < 32 * 64; i += 8192) {
        int ch = i >> 6, k = i & 63;
        int s = (k >> 5) & 1, kg = (k >> 3) & 3, j = (k >> 1) & 3, ci = k & 1;
        int tap = 0; bool val = true;
        if (!s)            tap = kg * 5 + j;        // rows 0-3, cols 0-3
        else if (kg == 0)  tap = 20 + j;            // row 4, cols 0-3
        else if (kg == 1)  tap = j * 5 + 4;         // col 4, rows 0-3
        else if (kg == 2) { tap = 24; val = (j == 0); }   // corner (4,4)
        else               val = false;
        w1c[i] = val ? f2bf(w1[(ch * 2 + ci) * 25 + tap]) : (unsigned short)0;
    }
    // w2t[tap25][f16][chpos32]: chpos 2i -> ch i, 2i+1 -> ch 16+i; f>=9 zero
    for (int i = gid; i < 25 * 16 * 32; i += 8192) {
        int p = i & 31;
        int f = (i >> 5) & 15;
        int tap = i >> 9;   // 0..24
        int ch = (p & 1) * 16 + (p >> 1);
        w2t[i] = (f < 9) ? f2bf(w2[(f * 32 + ch) * 25 + tap]) : (unsigned short)0;
    }
}

// conv2 pass over single tap-col TC0: rolling 4-row B-frag buffer.
// B-frag(row = wv*4 + i + tr, col = n + TC0) shared across (i,tr) with equal
// i+tr; rows rotate through R[.&3]. All indices compile-time after unroll.
template<int TC0>
__device__ __forceinline__ void conv2_pass(const unsigned short* hsp,
                                           const unsigned short* __restrict__ w2t,
                                           int wv, int n, int kg, f32x4* acc) {
    bf16x8 R[4];
    #pragma unroll
    for (int q = 0; q < 4; ++q)
        R[q] = *(const bf16x8*)(hsp + ((wv * 4 + q) * HS_C + n + TC0) * PXS + kg * 8);
    #pragma unroll
    for (int tr = 0; tr < 5; ++tr) {
        bf16x8 afr = *(const bf16x8*)(w2t + ((tr * 5 + TC0) * 16 + n) * 32 + kg * 8);
        #pragma unroll
        for (int i = 0; i < 4; ++i)
            acc[i] = __builtin_amdgcn_mfma_f32_16x16x32_bf16(afr, R[(tr + i) & 3], acc[i], 0, 0, 0);
        if (tr < 4)
            R[tr & 3] = *(const bf16x8*)(hsp + ((wv * 4 + tr + 4) * HS_C + n + TC0) * PXS + kg * 8);
    }
}

__global__
__attribute__((amdgpu_flat_work_group_size(256, 256), amdgpu_waves_per_eu(2)))
void dynfilt_main(const float* __restrict__ image,
                  const float* __restrict__ refer,
                  const float* __restrict__ b1,
                  const float* __restrict__ b2,
                  const unsigned short* __restrict__ w1c,
                  const unsigned short* __restrict__ w2t,
                  float* __restrict__ out)
{
    __shared__ float xs0f[XS_H * XSF];          // image fp32, stride-39 rows
    __shared__ unsigned int pxc[XS_N];          // packed (bf16 img | bf16 ref)
    __shared__ __align__(16) unsigned short hs[HS_R * HS_C * PXS];

    const int t   = threadIdx.x;
    const int gx0 = blockIdx.x * TILE;
    const int gy0 = blockIdx.y * TILE;

    // ---- batch-invariant staging offsets (sentinel -1 = skip) ----
    int soff[3];
    #pragma unroll
    for (int k = 0; k < 3; ++k) {
        int idx = t + k * 256;
        int r = idx / XS_W, c = idx - (idx / XS_W) * XS_W;
        int gy = gy0 - 4 + r, gx = gx0 - 4 + c;
        bool inb = (idx < XS_N) & ((unsigned)gy < HH) & ((unsigned)gx < WW);
        soff[k] = inb ? (gy * WW + gx) : -1;
    }

    const int lane = t & 63;
    const int wv   = t >> 6;
    const int n    = lane & 15;
    const int kg   = lane >> 4;

    // ---- conv1 B-frags: loaded ONCE, carried (w1c L1-hot) ----
    bf16x8 bfr[2][2];
    #pragma unroll
    for (int nt = 0; nt < 2; ++nt)
        #pragma unroll
        for (int s = 0; s < 2; ++s)
            bfr[nt][s] = *(const bf16x8*)(w1c + (nt * 16 + n) * 64 + s * 32 + kg * 8);

    // ---- a1 gather offsets (k-perm layout), packed 4x8bit; invalid -> 0
    //      (broadcast read, zero weight in w1c makes the product exact-0) ----
    unsigned int a1opk = 0;
    #pragma unroll
    for (int j = 0; j < 4; ++j) {
        int o = (kg == 0) ? (4 * XS_W + j)                  // row 4, col j
              : (kg == 1) ? (j * XS_W + 4)                  // row j, col 4
              : (kg == 2 && j == 0) ? (4 * XS_W + 4) : 0;   // corner / dummy
        a1opk |= (unsigned)o << (8 * j);
    }

    // ---- batch-invariant conv1 OOB mask: bit (m*4+r) = h px in-bounds ----
    // px = m*64 + wv*16 + kg*4 + r; divisions happen ONCE per block here,
    // never in the batch loop. Interior blocks get all-ones.
    unsigned int obmask = 0;
    #pragma unroll
    for (int m = 0; m < 7; ++m) {
        #pragma unroll
        for (int r = 0; r < 4; ++r) {
            int px = m * 64 + wv * 16 + kg * 4 + r;
            if (px < 400) {
                int prr = px / HS_C, pcc = px - prr * HS_C;
                int gy = gy0 - 2 + prr, gx = gx0 - 2 + pcc;
                if (((unsigned)gy < HH) & ((unsigned)gx < WW))
                    obmask |= 1u << (m * 4 + r);
            }
        }
    }

    // px = mt*16 + n raster start (pr0,pc0) over 20-wide h grid
    int px0 = wv * 16 + n;
    const int pr0 = px0 / 20, pc0 = px0 - (px0 / 20) * 20;

    const float bb0 = b1[n], bb1 = b1[16 + n];

    // ---- conv2 / epilogue constants (once); eo packed 4x8bit.
    //      Valid f: eo = (fy+3)*39 + fx+3. Invalid f>=9: bank-filler slots
    //      computed arithmetically: idx=f-9 -> e = 137+idx+4*((idx+1)/3)
    //      = {137,138,143,144,145,150,151}; all reads 2 lanes/bank. ----
    float b2r[4];
    unsigned int eopk = 0;
    #pragma unroll
    for (int r2 = 0; r2 < 4; ++r2) {
        int f = kg * 4 + r2;
        b2r[r2] = (f < 9) ? b2[f] : 0.f;
        unsigned int e;
        if (f < 9) {
            int fy = f / 3, fx = f - fy * 3;
            e = (unsigned)((fy + 3) * XSF + fx + 3);   // 120..200
        } else {
            int idx = f - 9;                           // 0..6
            e = 137u + (unsigned)idx + 4u * (unsigned)((idx + 1) / 3);
        }
        eopk |= e << (8 * r2);
    }

    // ---- prefetch batch 0 halo into regs ----
    float pvI[3], pvR[3];
    #pragma unroll
    for (int k = 0; k < 3; ++k) {
        pvI[k] = 0.f; pvR[k] = 0.f;
        if (soff[k] >= 0) {
            pvI[k] = image[soff[k]];
            pvR[k] = refer[soff[k]];
        }
    }

    #pragma unroll 1
    for (int bb = 0; bb < 8; ++bb) {
        // ---- stage write from prefetch regs ----
        #pragma unroll
        for (int k = 0; k < 3; ++k) {
            int idx = t + k * 256;
            if (idx < XS_N) {
                int r = idx / XS_W, c = idx - (idx / XS_W) * XS_W;
                xs0f[r * XSF + c] = pvI[k];
                pxc[idx] = pack_bf2(pvI[k], pvR[k]);
            }
        }
        __syncthreads();   // A: xs0f/pxc ready

        // ---- issue next batch's prefetch (hides under conv1+conv2) ----
        if (bb < 7) {
            const float* ibn = image + (size_t)(bb + 1) * (HH * WW);
            const float* rbn = refer + (size_t)(bb + 1) * (HH * WW);
            #pragma unroll
            for (int k = 0; k < 3; ++k) {
                pvI[k] = 0.f; pvR[k] = 0.f;
                if (soff[k] >= 0) {
                    pvI[k] = ibn[soff[k]];
                    pvR[k] = rbn[soff[k]];
                }
            }
        }

        // ---- unpack a1 offsets (conv1-local regs) ----
        int a1o[4];
        #pragma unroll
        for (int j = 0; j < 4; ++j)
            a1o[j] = (int)((a1opk >> (8 * j)) & 0xFFu);

        // ---- conv1 GEMM + fused leaky+pack write to hs (UNIFIED path) ----
        int pr = pr0, pc = pc0;
        unsigned short* hp0 = hs + (wv * 16 + kg * 4) * PXS + 2 * n;
        #pragma unroll
        for (int m = 0; m < 7; ++m) {
            int mt = m * 4 + wv;
            if (mt < 25) {   // wave-uniform guard
                const unsigned int* base = pxc + (pr * XS_W + pc);
                const unsigned int* a0p  = base + kg * XS_W;   // row kg
                unsigned int a0d[4], a1d[4];
                #pragma unroll
                for (int j = 0; j < 4; ++j) a0d[j] = a0p[j];
                #pragma unroll
                for (int j = 0; j < 4; ++j) a1d[j] = base[a1o[j]];
                bf16x8 a0 = dw4_to_frag(a0d[0], a0d[1], a0d[2], a0d[3]);
                bf16x8 a1 = dw4_to_frag(a1d[0], a1d[1], a1d[2], a1d[3]);
                f32x4 d0 = (f32x4){bb0, bb0, bb0, bb0};
                f32x4 d1 = (f32x4){bb1, bb1, bb1, bb1};
                d0 = __builtin_amdgcn_mfma_f32_16x16x32_bf16(a0, bfr[0][0], d0, 0, 0, 0);
                d0 = __builtin_amdgcn_mfma_f32_16x16x32_bf16(a1, bfr[0][1], d0, 0, 0, 0);
                d1 = __builtin_amdgcn_mfma_f32_16x16x32_bf16(a0, bfr[1][0], d1, 0, 0, 0);
                d1 = __builtin_amdgcn_mfma_f32_16x16x32_bf16(a1, bfr[1][1], d1, 0, 0, 0);
                #pragma unroll
                for (int r = 0; r < 4; ++r) {
                    float h0 = fmaxf(d0[r], 0.1f * d0[r]);
                    float h1 = fmaxf(d1[r], 0.1f * d1[r]);
                    if (!((obmask >> (m * 4 + r)) & 1u)) { h0 = 0.f; h1 = 0.f; }
                    *(unsigned int*)(hp0 + (m * 64 + r) * PXS) = pack_bf2(h0, h1);
                }
            }
            pc += 4; pr += 3;
            int w = (pc >= 20) ? 1 : 0;
            pc -= 20 * w; pr += w;
        }
        __syncthreads();   // B: hs ready

        // ---- conv2: rolling-row MFMA GEMM (5 single-col passes), b2-init ----
        f32x4 acc[4];
        #pragma unroll
        for (int i = 0; i < 4; ++i)
            acc[i] = (f32x4){b2r[0], b2r[1], b2r[2], b2r[3]};

        conv2_pass<0>(hs, w2t, wv, n, kg, acc);
        conv2_pass<1>(hs, w2t, wv, n, kg, acc);
        conv2_pass<2>(hs, w2t, wv, n, kg, acc);
        conv2_pass<3>(hs, w2t, wv, n, kg, acc);
        conv2_pass<4>(hs, w2t, wv, n, kg, acc);

        // ---- epilogue: out = sum_f filt_f * image[y+fy-1][x+fx-1] ----
        int eo[4];
        #pragma unroll
        for (int r2 = 0; r2 < 4; ++r2)
            eo[r2] = (int)((eopk >> (8 * r2)) & 0xFFu);
        #pragma unroll
        for (int i = 0; i < 4; ++i) {
            int py = wv * 4 + i;
            const float* xb = xs0f + py * XSF + n;
            float partial = 0.f;
            #pragma unroll
            for (int r2 = 0; r2 < 4; ++r2)
                partial += acc[i][r2] * xb[eo[r2]];   // f>=9 term exact-zero
            partial += __shfl_down(partial, 16, 64);
            partial += __shfl_down(partial, 32, 64);
            if (lane < 16)
                out[((size_t)bb * HH + gy0 + py) * WW + gx0 + n] = partial;
        }
        __syncthreads();   // C: xs0f/pxc/hs free for next batch
    }
}

extern "C" void kernel_launch(void* const* d_in, const int* in_sizes, int n_in,
                              void* d_out, int out_size, void* d_ws, size_t ws_size,
                              hipStream_t stream) {
    const float* image = (const float*)d_in[0];
    const float* refer = (const float*)d_in[1];
    const float* w1    = (const float*)d_in[2];
    const float* b1    = (const float*)d_in[3];
    const float* w2    = (const float*)d_in[4];
    const float* b2    = (const float*)d_in[5];

    unsigned short* w1c = (unsigned short*)d_ws;                   // 4 KB
    unsigned short* w2t = (unsigned short*)((char*)d_ws + 4096);   // 25.6 KB
    // ws re-poisoned before every launch -> prep must (and does) run every call

    hipLaunchKernelGGL(dynfilt_prep, dim3(32), dim3(256), 0, stream, w1, w2, w1c, w2t);

    dim3 grid(WW / TILE, HH / TILE, 1);   // persistent over batch: 1024 blocks
    hipLaunchKernelGGL(dynfilt_main, grid, dim3(256), 0, stream,
                       image, refer, b1, b2, w1c, w2t, (float*)d_out);
}